// Round 7
// baseline (225.022 us; speedup 1.0000x reference)
//
#include <hip/hip_runtime.h>
#include <hip/hip_bf16.h>

#define N_ROWS 32768
#define M_ROWS 8192
#define D_DIM  384
#define K_NB   9
#define BN     64
#define MQ     (M_ROWS / 4)      // 2048 cols per block
#define TILES  (MQ / BN)         // 32
#define KP     6                 // K pair-steps (384 / 64)

#define QRANGE 2048.0f
#define QSCALE (1.0f / 2048.0f)
#define QSTEPF (QRANGE / 65535.0f)
#define M2S    (-2.0f * QSCALE)
#define BIGF   3.0e38f

#define YS_OFF 49152             // LDS byte offset of Ys region

typedef long i64;
typedef __attribute__((ext_vector_type(2))) long i64x2;
typedef __attribute__((ext_vector_type(4))) float f32x4;
typedef __attribute__((ext_vector_type(4))) unsigned u32x4;

// ---- prep: f32 -> permuted fp8(e4m3) rows + exact f32 norms ----
// sigma per 384-elem row: byte p = kp*64 + grp*16 + half*8 + j  holds
// element k = kp*64 + half*32 + grp*8 + j  ->  16B chunk at (kp*64+grp*16)
// is lane (sub,grp)'s fragments for kk=2kp,2kp+1.
__global__ __launch_bounds__(256) void FAPM_prep8(
    const float* __restrict__ emb, const float* __restrict__ mem,
    unsigned* __restrict__ A8, unsigned* __restrict__ B8,
    float* __restrict__ xn, float* __restrict__ yn) {
  const int lane = threadIdx.x & 63;
  const int row  = blockIdx.x * 4 + (threadIdx.x >> 6);
  const float* src;
  unsigned* dst;
  float* nptr;
  if (row < N_ROWS) {
    src = emb + (size_t)row * D_DIM; dst = A8 + (size_t)row * 96; nptr = xn + row;
  } else {
    int r = row - N_ROWS;
    src = mem + (size_t)r * D_DIM; dst = B8 + (size_t)r * 96; nptr = yn + r;
  }
  float s = 0.f;
  {
    int dw = lane;
    int kp = dw >> 4, r4 = dw & 15;
    int grp = r4 >> 2, half = (r4 >> 1) & 1, j = (r4 & 1) * 4;
    int k0 = kp * 64 + half * 32 + grp * 8 + j;
    f32x4 v = *(const f32x4*)(src + k0);
    s += v.x * v.x + v.y * v.y + v.z * v.z + v.w * v.w;
    int pk = __builtin_amdgcn_cvt_pk_fp8_f32(v.x, v.y, 0, false);
    pk = __builtin_amdgcn_cvt_pk_fp8_f32(v.z, v.w, pk, true);
    dst[dw] = (unsigned)pk;
  }
  if (lane < 32) {
    int dw = lane + 64;
    int kp = dw >> 4, r4 = dw & 15;
    int grp = r4 >> 2, half = (r4 >> 1) & 1, j = (r4 & 1) * 4;
    int k0 = kp * 64 + half * 32 + grp * 8 + j;
    f32x4 v = *(const f32x4*)(src + k0);
    s += v.x * v.x + v.y * v.y + v.z * v.z + v.w * v.w;
    int pk = __builtin_amdgcn_cvt_pk_fp8_f32(v.x, v.y, 0, false);
    pk = __builtin_amdgcn_cvt_pk_fp8_f32(v.z, v.w, pk, true);
    dst[dw] = (unsigned)pk;
  }
#pragma unroll
  for (int dd = 1; dd < 64; dd <<= 1) s += __shfl_xor(s, dd);
  if (lane == 0) *nptr = s;
}

// packed u16 min/max (guaranteed codegen)
__device__ __forceinline__ unsigned pkmin(unsigned a, unsigned b) {
  unsigned d;
  asm("v_pk_min_u16 %0, %1, %2" : "=v"(d) : "v"(a), "v"(b));
  return d;
}
__device__ __forceinline__ unsigned pkmax(unsigned a, unsigned b) {
  unsigned d;
  asm("v_pk_max_u16 %0, %1, %2" : "=v"(d) : "v"(a), "v"(b));
  return d;
}

// ---- 16-lane merge of per-lane sorted u16 lists; writes f32 d^2 ascending ----
__device__ __forceinline__ void merge16i(unsigned t[9], float* dst, int sub) {
  for (int s = 0; s < K_NB; ++s) {
    unsigned m  = t[0];
    int      ml = sub;
#pragma unroll
    for (int dd = 1; dd < 16; dd <<= 1) {
      unsigned ov = (unsigned)__shfl_xor((int)m, dd);
      int      ol = __shfl_xor(ml, dd);
      bool take = (ov < m) || (ov == m && ol < ml);
      m  = take ? ov : m;
      ml = take ? ol : ml;
    }
    if (sub == ml) {
#pragma unroll
      for (int j = 0; j < 8; ++j) t[j] = t[j + 1];
      t[8] = 0xFFFFu;
    }
    if (sub == 0) dst[s] = (float)m * QSTEPF;
  }
}

// ------- fused: A in regs, B double-buffered, cb-outer with fused topk -------
__global__ __launch_bounds__(256, 3) void FAPM_fused(
    const unsigned char* __restrict__ A8, const unsigned char* __restrict__ B8,
    const float* __restrict__ xn, const float* __restrict__ yn,
    float* __restrict__ part) {
  // [0,48K): A stage (prologue), then B buf0 [0,24K) / buf1 [24K,48K)
  // [48K,52K): Ys as unorm16 (2048 entries)
  __shared__ __attribute__((aligned(128))) unsigned char LDS[53248];
  const int tid  = threadIdx.x;
  const int lane = tid & 63;
  const int w    = tid >> 6;
  const int sub  = lane & 15;
  const int grp  = lane >> 4;
  const int bx   = blockIdx.x;
  const int mq   = bx & 3;
  const int wrow0 = (bx >> 2) * 128 + w * 32;
  const int colbase = mq * MQ;

  float xs0[4], xs1[4];
#pragma unroll
  for (int i = 0; i < 4; ++i) {
    xs0[i] = xn[wrow0 + grp * 4 + i] * QSCALE;
    xs1[i] = xn[wrow0 + 16 + grp * 4 + i] * QSCALE;
  }

  // ---- Ys region: 8 y-norms per thread -> unorm16 ----
  {
    const float* yp = yn + colbase + tid * 8;
    f32x4 v0 = *(const f32x4*)yp;
    f32x4 v1 = *(const f32x4*)(yp + 4);
    float a0 = v0.x * QSCALE, a1 = v0.y * QSCALE, a2 = v0.z * QSCALE, a3 = v0.w * QSCALE;
    float a4 = v1.x * QSCALE, a5 = v1.y * QSCALE, a6 = v1.z * QSCALE, a7 = v1.w * QSCALE;
    unsigned q0, q1, q2, q3;
    asm("v_cvt_pknorm_u16_f32 %0, %1, %2" : "=v"(q0) : "v"(a0), "v"(a1));
    asm("v_cvt_pknorm_u16_f32 %0, %1, %2" : "=v"(q1) : "v"(a2), "v"(a3));
    asm("v_cvt_pknorm_u16_f32 %0, %1, %2" : "=v"(q2) : "v"(a4), "v"(a5));
    asm("v_cvt_pknorm_u16_f32 %0, %1, %2" : "=v"(q3) : "v"(a6), "v"(a7));
    *(u32x4*)(&LDS[YS_OFF + tid * 16]) = (u32x4){q0, q1, q2, q3};
  }

  // ---- stage A (once): wave w fills its 12 subtiles ----
  {
    const unsigned char* asrc = A8 + (size_t)(wrow0 + sub) * D_DIM + grp * 16;
#pragma unroll
    for (int rb = 0; rb < 2; ++rb)
#pragma unroll
      for (int q = 0; q < KP; ++q)
        __builtin_amdgcn_global_load_lds(
            (const __attribute__((address_space(1))) void*)(asrc + rb * 16 * D_DIM + q * 64),
            (__attribute__((address_space(3))) void*)(LDS + ((w * 2 + rb) * KP + q) * 1024),
            16, 0, 0);
  }
  asm volatile("s_waitcnt vmcnt(0)" ::: "memory");
  __syncthreads();

  // ---- A LDS -> registers (forced resident: LDS below is rewritten) ----
  i64 af0[12], af1[12];
  {
    const unsigned char* ar0 = LDS + (w * 2) * (KP * 1024) + lane * 16;
    const unsigned char* ar1 = ar0 + KP * 1024;
#pragma unroll
    for (int kp = 0; kp < KP; ++kp) {
      i64x2 v0 = *(const i64x2*)(ar0 + kp * 1024);
      i64x2 v1 = *(const i64x2*)(ar1 + kp * 1024);
      af0[2 * kp] = v0.x; af0[2 * kp + 1] = v0.y;
      af1[2 * kp] = v1.x; af1[2 * kp + 1] = v1.y;
    }
  }
  __syncthreads();  // all waves done reading A region; reuse as B buffers

  // ---- prime the 2-deep B pipeline ----
  const unsigned char* bsrc = B8 + (size_t)(colbase + w * 16 + sub) * D_DIM + grp * 16;
#pragma unroll
  for (int q = 0; q < KP; ++q)
    __builtin_amdgcn_global_load_lds(
        (const __attribute__((address_space(1))) void*)(bsrc + q * 64),
        (__attribute__((address_space(3))) void*)(LDS + (w * KP + q) * 1024),
        16, 0, 0);
#pragma unroll
  for (int q = 0; q < KP; ++q)
    __builtin_amdgcn_global_load_lds(
        (const __attribute__((address_space(1))) void*)(bsrc + 24576 + q * 64),
        (__attribute__((address_space(3))) void*)(LDS + 24576 + (w * KP + q) * 1024),
        16, 0, 0);
  bsrc += 2 * 24576;

  unsigned tkp[4][9];  // packed (rowblock0 lo, rowblock1 hi) top-9, quantized d^2
#pragma unroll
  for (int i = 0; i < 4; ++i)
#pragma unroll
    for (int j = 0; j < 9; ++j) tkp[i][j] = 0xFFFFFFFFu;

  for (int t = 0; t < TILES; ++t) {
    const int bufo = (t & 1) * 24576;
    if (t + 1 < TILES) asm volatile("s_waitcnt vmcnt(6)" ::: "memory");
    else               asm volatile("s_waitcnt vmcnt(0)" ::: "memory");
    __builtin_amdgcn_s_barrier();

    const unsigned char* br = LDS + bufo + lane * 16;
    // cb-outer: 24 MFMAs then topk for that cb — VALU rides inside the
    // MFMA region, so co-resident waves keep the matrix pipe fed.
#pragma unroll
    for (int cb = 0; cb < 4; ++cb) {
      unsigned yu = *(const unsigned short*)(
          &LDS[YS_OFF + ((t * 64 + cb * 16 + sub) << 1)]);
      float ysv = (float)yu * (1.0f / 65535.0f);

      f32x4 acc0 = {0.f, 0.f, 0.f, 0.f}, acc1 = {0.f, 0.f, 0.f, 0.f};
      __builtin_amdgcn_s_setprio(1);
#pragma unroll
      for (int kp = 0; kp < KP; ++kp) {
        i64x2 b = *(const i64x2*)(br + (cb * KP + kp) * 1024);
        acc0 = __builtin_amdgcn_mfma_f32_16x16x32_fp8_fp8(af0[2 * kp], b.x, acc0, 0, 0, 0);
        acc1 = __builtin_amdgcn_mfma_f32_16x16x32_fp8_fp8(af1[2 * kp], b.x, acc1, 0, 0, 0);
        acc0 = __builtin_amdgcn_mfma_f32_16x16x32_fp8_fp8(af0[2 * kp + 1], b.y, acc0, 0, 0, 0);
        acc1 = __builtin_amdgcn_mfma_f32_16x16x32_fp8_fp8(af1[2 * kp + 1], b.y, acc1, 0, 0, 0);
      }
      __builtin_amdgcn_s_setprio(0);

#pragma unroll
      for (int i = 0; i < 4; ++i) {
        float d2a = fmaf(acc0[i], M2S, xs0[i] + ysv);
        float d2b = fmaf(acc1[i], M2S, xs1[i] + ysv);
        unsigned dp;
        asm("v_cvt_pknorm_u16_f32 %0, %1, %2" : "=v"(dp) : "v"(d2a), "v"(d2b));
#pragma unroll
        for (int j = 8; j >= 1; --j)
          tkp[i][j] = pkmin(tkp[i][j], pkmax(dp, tkp[i][j - 1]));
        tkp[i][0] = pkmin(tkp[i][0], dp);
      }
    }
    __builtin_amdgcn_s_barrier();  // all waves done reading buf[t&1]

    // refill buf[t&1] with tile t+2 (in flight across next barrier)
    if (t + 2 < TILES) {
#pragma unroll
      for (int q = 0; q < KP; ++q)
        __builtin_amdgcn_global_load_lds(
            (const __attribute__((address_space(1))) void*)(bsrc + q * 64),
            (__attribute__((address_space(3))) void*)(LDS + bufo + (w * KP + q) * 1024),
            16, 0, 0);
      bsrc += 24576;
    }
  }

  // ---- unpack + per-row merge across 16 sub-lanes; write f32 d^2 partials ----
  float* pbase = part + (size_t)mq * N_ROWS * K_NB;
#pragma unroll
  for (int i = 0; i < 4; ++i) {
    unsigned ta[9], tb[9];
#pragma unroll
    for (int j = 0; j < 9; ++j) { ta[j] = tkp[i][j] & 0xFFFFu; tb[j] = tkp[i][j] >> 16; }
    merge16i(ta, pbase + (size_t)(wrow0 + grp * 4 + i) * K_NB, sub);
    merge16i(tb, pbase + (size_t)(wrow0 + 16 + grp * 4 + i) * K_NB, sub);
  }
}

// ------- merge the four M-quarter partials, sqrt, final output -------
__global__ __launch_bounds__(256) void FAPM_merge4(
    const float* __restrict__ part, float* __restrict__ out) {
  const int r = blockIdx.x * 256 + threadIdx.x;
  float l[4][9];
#pragma unroll
  for (int q = 0; q < 4; ++q)
#pragma unroll
    for (int j = 0; j < 9; ++j)
      l[q][j] = part[(size_t)q * N_ROWS * K_NB + (size_t)r * K_NB + j];
#pragma unroll
  for (int s = 0; s < K_NB; ++s) {
    float m = fminf(fminf(l[0][0], l[1][0]), fminf(l[2][0], l[3][0]));
    out[(size_t)r * K_NB + s] = sqrtf(fmaxf(m, 0.f));
    bool t0 = (l[0][0] == m);
    bool t1 = (l[1][0] == m) && !t0;
    bool t2 = (l[2][0] == m) && !t0 && !t1;
    bool t3 = !(t0 || t1 || t2);
#pragma unroll
    for (int j = 0; j < 8; ++j) {
      l[0][j] = t0 ? l[0][j + 1] : l[0][j];
      l[1][j] = t1 ? l[1][j + 1] : l[1][j];
      l[2][j] = t2 ? l[2][j + 1] : l[2][j];
      l[3][j] = t3 ? l[3][j + 1] : l[3][j];
    }
    l[0][8] = t0 ? BIGF : l[0][8];
    l[1][8] = t1 ? BIGF : l[1][8];
    l[2][8] = t2 ? BIGF : l[2][8];
    l[3][8] = t3 ? BIGF : l[3][8];
  }
}

extern "C" void kernel_launch(void* const* d_in, const int* in_sizes, int n_in,
                              void* d_out, int out_size, void* d_ws, size_t ws_size,
                              hipStream_t stream) {
  const float* emb = (const float*)d_in[0];
  const float* mem = (const float*)d_in[1];
  float* out = (float*)d_out;
  char* ws = (char*)d_ws;
  size_t offA = 0;
  size_t offB = offA + (size_t)N_ROWS * D_DIM;       // A8: 12,582,912
  size_t offX = offB + (size_t)M_ROWS * D_DIM;       // B8: +3,145,728
  size_t offY = offX + (size_t)N_ROWS * 4;           // +131,072
  size_t offP = offY + (size_t)M_ROWS * 4;           // +32,768
  unsigned char* A8 = (unsigned char*)(ws + offA);
  unsigned char* B8 = (unsigned char*)(ws + offB);
  float* xn = (float*)(ws + offX);
  float* yn = (float*)(ws + offY);
  float* part = (float*)(ws + offP);

  FAPM_prep8<<<(N_ROWS + M_ROWS) / 4, 256, 0, stream>>>(
      emb, mem, (unsigned*)A8, (unsigned*)B8, xn, yn);
  FAPM_fused<<<(N_ROWS / 128) * 4, 256, 0, stream>>>(A8, B8, xn, yn, part);
  FAPM_merge4<<<N_ROWS / 256, 256, 0, stream>>>(part, out);
}

// Round 9
// 192.482 us; speedup vs baseline: 1.1691x; 1.1691x over previous
//
#include <hip/hip_runtime.h>
#include <hip/hip_bf16.h>

#define N_ROWS 32768
#define M_ROWS 8192
#define D_DIM  384
#define K_NB   9
#define BN     64
#define BM     256
#define MQ     (M_ROWS / 4)      // 2048 cols per block
#define TILES  (MQ / BN)         // 32
#define KS     3                 // K steps of 128

// key = y^2 - 2xy quantized: key' = (key + 256) / 2048 in [0,1]
#define QSCALE (1.0f / 2048.0f)
#define YOFF   0.125f            // 256/2048
#define QSTEPF (2048.0f / 65535.0f)
#define QOFFB  256.0f
#define M2S    (-2.0f / 2048.0f)
#define BIGF   3.0e38f

#define YS_OFF 49152             // LDS byte offset of Ys region

typedef __attribute__((ext_vector_type(4))) int      i32x4;
typedef __attribute__((ext_vector_type(8))) int      i32x8;
typedef __attribute__((ext_vector_type(4))) float    f32x4;
typedef __attribute__((ext_vector_type(4))) unsigned u32x4;

#define GLDS(SRC, DST)                                                       \
  __builtin_amdgcn_global_load_lds(                                          \
      (const __attribute__((address_space(1))) void*)(SRC),                  \
      (__attribute__((address_space(3))) void*)(DST), 16, 0, 0)

// ---- prep: f32 -> fp8(e4m3) rows (k-linear) + exact f32 norms ----
__global__ __launch_bounds__(256) void FAPM_prep8(
    const float* __restrict__ emb, const float* __restrict__ mem,
    unsigned* __restrict__ A8, unsigned* __restrict__ B8,
    float* __restrict__ xn, float* __restrict__ yn) {
  const int lane = threadIdx.x & 63;
  const int row  = blockIdx.x * 4 + (threadIdx.x >> 6);
  const float* src;
  unsigned* dst;
  float* nptr;
  if (row < N_ROWS) {
    src = emb + (size_t)row * D_DIM; dst = A8 + (size_t)row * 96; nptr = xn + row;
  } else {
    int r = row - N_ROWS;
    src = mem + (size_t)r * D_DIM; dst = B8 + (size_t)r * 96; nptr = yn + r;
  }
  float s = 0.f;
  {
    int dw = lane;  // dwords 0..63
    f32x4 v = *(const f32x4*)(src + dw * 4);
    s += v.x * v.x + v.y * v.y + v.z * v.z + v.w * v.w;
    int pk = __builtin_amdgcn_cvt_pk_fp8_f32(v.x, v.y, 0, false);
    pk = __builtin_amdgcn_cvt_pk_fp8_f32(v.z, v.w, pk, true);
    dst[dw] = (unsigned)pk;
  }
  if (lane < 32) {
    int dw = lane + 64;  // dwords 64..95
    f32x4 v = *(const f32x4*)(src + dw * 4);
    s += v.x * v.x + v.y * v.y + v.z * v.z + v.w * v.w;
    int pk = __builtin_amdgcn_cvt_pk_fp8_f32(v.x, v.y, 0, false);
    pk = __builtin_amdgcn_cvt_pk_fp8_f32(v.z, v.w, pk, true);
    dst[dw] = (unsigned)pk;
  }
#pragma unroll
  for (int dd = 1; dd < 64; dd <<= 1) s += __shfl_xor(s, dd);
  if (lane == 0) *nptr = s;
}

// packed u16 min/max
__device__ __forceinline__ unsigned pkmin(unsigned a, unsigned b) {
  unsigned d;
  asm("v_pk_min_u16 %0, %1, %2" : "=v"(d) : "v"(a), "v"(b));
  return d;
}
__device__ __forceinline__ unsigned pkmax(unsigned a, unsigned b) {
  unsigned d;
  asm("v_pk_max_u16 %0, %1, %2" : "=v"(d) : "v"(a), "v"(b));
  return d;
}

// ---- 16-lane merge of per-lane sorted u16 lists; writes f32 key ascending ----
__device__ __forceinline__ void merge16i(unsigned t[9], float* dst, int sub) {
  for (int s = 0; s < K_NB; ++s) {
    unsigned m  = t[0];
    int      ml = sub;
#pragma unroll
    for (int dd = 1; dd < 16; dd <<= 1) {
      unsigned ov = (unsigned)__shfl_xor((int)m, dd);
      int      ol = __shfl_xor(ml, dd);
      bool take = (ov < m) || (ov == m && ol < ml);
      m  = take ? ov : m;
      ml = take ? ol : ml;
    }
    if (sub == ml) {
#pragma unroll
      for (int j = 0; j < 8; ++j) t[j] = t[j + 1];
      t[8] = 0xFFFFu;
    }
    if (sub == 0) dst[s] = (float)m * QSTEPF - QOFFB;  // key = y^2 - 2xy
  }
}

// ------- fused: MX-fp8 K=128 MFMA (scales=1), 64 rows/wave, key top-9 -------
__global__ __launch_bounds__(256, 2) void FAPM_fused(
    const unsigned char* __restrict__ A8, const unsigned char* __restrict__ B8,
    const float* __restrict__ yn, float* __restrict__ part) {
  // [0,48K): A stage (prologue, 128 rows/half), then B buf0/buf1 (24KB each)
  //   per (rb,ks) subtile: [h:2][64 lanes][16B]; lane's 32 k-bytes =
  //   ks*128 + (lane>>4)*32 .. +31 of row (lane&15).
  // [48K,52K): Ys as unorm16 of (y^2/2048 + 0.125)
  __shared__ __attribute__((aligned(128))) unsigned char LDS[53248];
  const int tid  = threadIdx.x;
  const int lane = tid & 63;
  const int w    = tid >> 6;          // wave 0..3
  const int sub  = lane & 15;
  const int grp  = lane >> 4;
  const int bx   = blockIdx.x;
  const int mq   = bx & 3;
  const int row0 = (bx >> 2) * BM;    // block rows; wave owns row0+w*64 .. +63
  const int colbase = mq * MQ;

  // ---- Ys region: 8 y-norms per thread -> unorm16 of key-offset form ----
  {
    const float* yp = yn + colbase + tid * 8;
    f32x4 v0 = *(const f32x4*)yp;
    f32x4 v1 = *(const f32x4*)(yp + 4);
    float a0 = fmaf(v0.x, QSCALE, YOFF), a1 = fmaf(v0.y, QSCALE, YOFF);
    float a2 = fmaf(v0.z, QSCALE, YOFF), a3 = fmaf(v0.w, QSCALE, YOFF);
    float a4 = fmaf(v1.x, QSCALE, YOFF), a5 = fmaf(v1.y, QSCALE, YOFF);
    float a6 = fmaf(v1.z, QSCALE, YOFF), a7 = fmaf(v1.w, QSCALE, YOFF);
    unsigned q0, q1, q2, q3;
    asm("v_cvt_pknorm_u16_f32 %0, %1, %2" : "=v"(q0) : "v"(a0), "v"(a1));
    asm("v_cvt_pknorm_u16_f32 %0, %1, %2" : "=v"(q1) : "v"(a2), "v"(a3));
    asm("v_cvt_pknorm_u16_f32 %0, %1, %2" : "=v"(q2) : "v"(a4), "v"(a5));
    asm("v_cvt_pknorm_u16_f32 %0, %1, %2" : "=v"(q3) : "v"(a6), "v"(a7));
    *(u32x4*)(&LDS[YS_OFF + tid * 16]) = (u32x4){q0, q1, q2, q3};
  }

  i32x8 af[4][KS];  // 96 VGPR: 4 row-blocks of 16, 3 K-steps of 128

  // ---- stage + read A, two halves of 128 rows through [0,48K) ----
#pragma unroll
  for (int half = 0; half < 2; ++half) {
    const unsigned char* asrc =
        A8 + (size_t)(row0 + half * 128 + (w * 2) * 16 + (lane & 15)) * D_DIM +
        (lane >> 4) * 32;
#pragma unroll
    for (int rb2 = 0; rb2 < 2; ++rb2)
#pragma unroll
      for (int ks = 0; ks < KS; ++ks)
#pragma unroll
        for (int h = 0; h < 2; ++h)
          GLDS(asrc + rb2 * 16 * D_DIM + ks * 128 + h * 16,
               LDS + (((w * 2 + rb2) * KS + ks) * 2 + h) * 1024);
    asm volatile("s_waitcnt vmcnt(0)" ::: "memory");
    __syncthreads();
    if ((w >> 1) == half) {
      const int rbh = (w & 1) * 4;
#pragma unroll
      for (int rbl = 0; rbl < 4; ++rbl)
#pragma unroll
        for (int ks = 0; ks < KS; ++ks) {
          const unsigned char* p =
              LDS + (((rbh + rbl) * KS + ks) * 2) * 1024 + lane * 16;
          *(i32x4*)&af[rbl][ks] = *(const i32x4*)p;
          *((i32x4*)&af[rbl][ks] + 1) = *(const i32x4*)(p + 1024);
        }
    }
    __syncthreads();  // reads drained (syncthreads waits lgkm) before overwrite
  }

  // ---- prime 2-deep B pipeline: ALL of tile 0 first, THEN all of tile 1,
  //      so vmcnt(6) at iter t means "tile t fully landed" (R8 bugfix) ----
  const unsigned char* bsrc =
      B8 + (size_t)(colbase + w * 16 + (lane & 15)) * D_DIM + (lane >> 4) * 32;
#pragma unroll
  for (int ks = 0; ks < KS; ++ks)
#pragma unroll
    for (int h = 0; h < 2; ++h)
      GLDS(bsrc + ks * 128 + h * 16, LDS + w * 6144 + (ks * 2 + h) * 1024);
#pragma unroll
  for (int ks = 0; ks < KS; ++ks)
#pragma unroll
    for (int h = 0; h < 2; ++h)
      GLDS(bsrc + 24576 + ks * 128 + h * 16,
           LDS + 24576 + w * 6144 + (ks * 2 + h) * 1024);
  bsrc += 2 * 24576;

  unsigned tkp[2][4][9];  // packed (rbl 2s lo, 2s+1 hi) top-9 keys
#pragma unroll
  for (int s2 = 0; s2 < 2; ++s2)
#pragma unroll
    for (int i = 0; i < 4; ++i)
#pragma unroll
      for (int j = 0; j < 9; ++j) tkp[s2][i][j] = 0xFFFFFFFFu;

  for (int t = 0; t < TILES; ++t) {
    const int bufo = (t & 1) * 24576;
    if (t + 1 < TILES) asm volatile("s_waitcnt vmcnt(6)" ::: "memory");
    else               asm volatile("s_waitcnt vmcnt(0)" ::: "memory");
    __builtin_amdgcn_s_barrier();

    const unsigned char* br = LDS + bufo + lane * 16;
#pragma unroll
    for (int cb = 0; cb < 4; ++cb) {
      unsigned yu = *(const unsigned short*)(
          &LDS[YS_OFF + ((t * 64 + cb * 16 + sub) << 1)]);
      float ysv = (float)yu * (1.0f / 65535.0f);

      i32x8 bf[KS];
#pragma unroll
      for (int ks = 0; ks < KS; ++ks) {
        const unsigned char* p = br + cb * 6144 + ks * 2048;
        *(i32x4*)&bf[ks] = *(const i32x4*)p;
        *((i32x4*)&bf[ks] + 1) = *(const i32x4*)(p + 1024);
      }
      f32x4 acc[4];
#pragma unroll
      for (int rbl = 0; rbl < 4; ++rbl) acc[rbl] = (f32x4){0.f, 0.f, 0.f, 0.f};
      __builtin_amdgcn_s_setprio(1);
#pragma unroll
      for (int ks = 0; ks < KS; ++ks)
#pragma unroll
        for (int rbl = 0; rbl < 4; ++rbl)
          acc[rbl] = __builtin_amdgcn_mfma_scale_f32_16x16x128_f8f6f4(
              af[rbl][ks], bf[ks], acc[rbl], 0, 0,
              0, 0x7F7F7F7F, 0, 0x7F7F7F7F);  // E8M0 scales = 1.0
      __builtin_amdgcn_s_setprio(0);

#pragma unroll
      for (int s2 = 0; s2 < 2; ++s2)
#pragma unroll
        for (int i = 0; i < 4; ++i) {
          float d2a = fmaf(acc[2 * s2][i], M2S, ysv);
          float d2b = fmaf(acc[2 * s2 + 1][i], M2S, ysv);
          unsigned dp;
          asm("v_cvt_pknorm_u16_f32 %0, %1, %2" : "=v"(dp) : "v"(d2a), "v"(d2b));
#pragma unroll
          for (int j = 8; j >= 1; --j)
            tkp[s2][i][j] = pkmin(tkp[s2][i][j], pkmax(dp, tkp[s2][i][j - 1]));
          tkp[s2][i][0] = pkmin(tkp[s2][i][0], dp);
        }
    }
    __builtin_amdgcn_s_barrier();  // all waves done reading buf[t&1]

    if (t + 2 < TILES) {
#pragma unroll
      for (int ks = 0; ks < KS; ++ks)
#pragma unroll
        for (int h = 0; h < 2; ++h)
          GLDS(bsrc + ks * 128 + h * 16,
               LDS + bufo + w * 6144 + (ks * 2 + h) * 1024);
      bsrc += 24576;
    }
  }

  // ---- unpack + per-row merge across 16 sub-lanes; write f32 key partials ----
  float* pbase = part + (size_t)mq * N_ROWS * K_NB;
#pragma unroll
  for (int s2 = 0; s2 < 2; ++s2)
#pragma unroll
    for (int i = 0; i < 4; ++i) {
      unsigned ta[9], tb[9];
#pragma unroll
      for (int j = 0; j < 9; ++j) {
        ta[j] = tkp[s2][i][j] & 0xFFFFu;
        tb[j] = tkp[s2][i][j] >> 16;
      }
      int rowA = row0 + w * 64 + (2 * s2) * 16 + grp * 4 + i;
      merge16i(ta, pbase + (size_t)rowA * K_NB, sub);
      merge16i(tb, pbase + (size_t)(rowA + 16) * K_NB, sub);
    }
}

// ------- merge the four M-quarter partials, add x^2, sqrt, final output -------
__global__ __launch_bounds__(256) void FAPM_merge4(
    const float* __restrict__ part, const float* __restrict__ xn,
    float* __restrict__ out) {
  const int r = blockIdx.x * 256 + threadIdx.x;
  const float xr = xn[r];
  float l[4][9];
#pragma unroll
  for (int q = 0; q < 4; ++q)
#pragma unroll
    for (int j = 0; j < 9; ++j)
      l[q][j] = part[(size_t)q * N_ROWS * K_NB + (size_t)r * K_NB + j];
#pragma unroll
  for (int s = 0; s < K_NB; ++s) {
    float m = fminf(fminf(l[0][0], l[1][0]), fminf(l[2][0], l[3][0]));
    out[(size_t)r * K_NB + s] = sqrtf(fmaxf(m + xr, 0.f));
    bool t0 = (l[0][0] == m);
    bool t1 = (l[1][0] == m) && !t0;
    bool t2 = (l[2][0] == m) && !t0 && !t1;
    bool t3 = !(t0 || t1 || t2);
#pragma unroll
    for (int j = 0; j < 8; ++j) {
      l[0][j] = t0 ? l[0][j + 1] : l[0][j];
      l[1][j] = t1 ? l[1][j + 1] : l[1][j];
      l[2][j] = t2 ? l[2][j + 1] : l[2][j];
      l[3][j] = t3 ? l[3][j + 1] : l[3][j];
    }
    l[0][8] = t0 ? BIGF : l[0][8];
    l[1][8] = t1 ? BIGF : l[1][8];
    l[2][8] = t2 ? BIGF : l[2][8];
    l[3][8] = t3 ? BIGF : l[3][8];
  }
}

extern "C" void kernel_launch(void* const* d_in, const int* in_sizes, int n_in,
                              void* d_out, int out_size, void* d_ws, size_t ws_size,
                              hipStream_t stream) {
  const float* emb = (const float*)d_in[0];
  const float* mem = (const float*)d_in[1];
  float* out = (float*)d_out;
  char* ws = (char*)d_ws;
  size_t offA = 0;
  size_t offB = offA + (size_t)N_ROWS * D_DIM;       // A8: 12,582,912
  size_t offX = offB + (size_t)M_ROWS * D_DIM;       // B8: +3,145,728
  size_t offY = offX + (size_t)N_ROWS * 4;           // +131,072
  size_t offP = offY + (size_t)M_ROWS * 4;           // +32,768
  // partials: 4 quarters x N x 9 f32 = 4,718,592  (total ~20.6 MB)
  unsigned char* A8 = (unsigned char*)(ws + offA);
  unsigned char* B8 = (unsigned char*)(ws + offB);
  float* xn = (float*)(ws + offX);
  float* yn = (float*)(ws + offY);
  float* part = (float*)(ws + offP);

  FAPM_prep8<<<(N_ROWS + M_ROWS) / 4, 256, 0, stream>>>(
      emb, mem, (unsigned*)A8, (unsigned*)B8, xn, yn);
  FAPM_fused<<<(N_ROWS / BM) * 4, 256, 0, stream>>>(A8, B8, yn, part);
  FAPM_merge4<<<N_ROWS / 256, 256, 0, stream>>>(part, xn, out);
}